// Round 1
// baseline (823.936 us; speedup 1.0000x reference)
//
#include <hip/hip_runtime.h>
#include <stdint.h>

#define NN 50000
#define NE 1600000
#define BE 128

typedef __attribute__((ext_vector_type(8))) short short8;
typedef __attribute__((ext_vector_type(4))) float f32x4;

__device__ __forceinline__ unsigned short f2bf(float f) {
    unsigned int u = __float_as_uint(f);
    u += 0x7fff + ((u >> 16) & 1);   // round-nearest-even
    return (unsigned short)(u >> 16);
}

__device__ __forceinline__ float silu_f(float v) {
    return v / (1.0f + __expf(-v));
}

// ws layout (ushort):
// [0,20480)      node_w1^T  [128][160]
// [20480,40960)  coord_w1^T [128][160]
// [40960,49152)  node_w2^T  [64][128]
__global__ void prep_kernel(const float* __restrict__ nw1,
                            const float* __restrict__ cw1,
                            const float* __restrict__ nw2,
                            unsigned short* __restrict__ ws) {
    int i = blockIdx.x * 256 + threadIdx.x;
    if (i < 20480) {
        int n = i / 160, k = i % 160;
        ws[i] = f2bf(nw1[k * 128 + n]);
    } else if (i < 40960) {
        int j = i - 20480; int n = j / 160, k = j % 160;
        ws[i] = f2bf(cw1[k * 128 + n]);
    } else if (i < 49152) {
        int j = i - 40960; int o = j / 128, k = j % 128;
        ws[i] = f2bf(nw2[k * 64 + o]);
    }
}

// out[0:3.2M] = h, out[3.2M:3.35M] = x   (both div by 4)
__global__ void init_out(const float4* __restrict__ h4,
                         const float4* __restrict__ x4,
                         float4* __restrict__ out4) {
    int i = blockIdx.x * 256 + threadIdx.x;
    if (i < 800000)       out4[i] = h4[i];
    else if (i < 837500)  out4[i] = x4[i - 800000];
}

#define MIS 168   // m_input row stride (ushorts); 336B = 21*16B -> aligned + bank-friendly

__global__ __launch_bounds__(256, 2)
void egnn_edge_kernel(const float* __restrict__ h,
                      const float* __restrict__ x,
                      const int* __restrict__ eidx,
                      const float* __restrict__ edist,
                      const float* __restrict__ node_b1,
                      const float* __restrict__ node_b2,
                      const float* __restrict__ coord_b1,
                      const float* __restrict__ coord_w2,
                      const float* __restrict__ ew1,
                      const float* __restrict__ eb1,
                      const float* __restrict__ ew2,
                      const float* __restrict__ eb2,
                      const unsigned short* __restrict__ ws,
                      float* __restrict__ out_h,
                      float* __restrict__ out_x) {
    // LDS: 128*168*2 + 64*168*2 = 64512 B -> 2 blocks/CU
    __shared__ unsigned short mi[BE * MIS];     // m_input tile, later hidden tile
    __shared__ unsigned short wbuf[64 * MIS];   // W1^T half (64 N-rows x 160 K)

    const int tid  = threadIdx.x;
    const int w    = tid >> 6;      // wave 0..3, owns edge rows [w*32, w*32+32)
    const int lane = tid & 63;
    const int ln   = lane & 15;
    const int quad = lane >> 4;
    const int e0   = blockIdx.x * BE;

    // ---- stage m_input cols 0..127: gather h[src], h[dst] as bf16 ----
    {
        const float4* h4 = (const float4*)h;
        const int g = tid >> 4, l16 = tid & 15;
        #pragma unroll
        for (int it = 0; it < 16; ++it) {
            int row = it * 16 + g;                 // 0..255: 0..127 src, 128..255 dst
            int e = row & 127;
            int node = (row < 128) ? eidx[e0 + e] : eidx[NE + e0 + e];
            int cbase = (row < 128) ? 0 : 64;
            float4 v = h4[node * 16 + l16];
            unsigned short b[4] = {f2bf(v.x), f2bf(v.y), f2bf(v.z), f2bf(v.w)};
            *(uint2*)&mi[e * MIS + cbase + l16 * 4] = *(uint2*)b;
        }
    }
    // ---- stage m_input cols 128..159: edge MLP (fp32) ----
    {
        int e = tid >> 1, half = tid & 1;
        float d = edist[e0 + e];
        float s[16];
        #pragma unroll
        for (int jj = 0; jj < 16; ++jj) s[jj] = eb2[half * 16 + jj];
        #pragma unroll
        for (int k = 0; k < 32; ++k) {
            float tk = silu_f(d * ew1[k] + eb1[k]);
            const float* r2 = ew2 + k * 32 + half * 16;
            #pragma unroll
            for (int jj = 0; jj < 16; ++jj) s[jj] += tk * r2[jj];
        }
        #pragma unroll
        for (int jj = 0; jj < 16; ++jj)
            mi[e * MIS + 128 + half * 16 + jj] = f2bf(s[jj]);
    }

    // ---- GEMM1 (both node and coord): [128,160] @ [160,128] ----
    f32x4 accN[2][8], accC[2][8];
    const f32x4 zero = {0.f, 0.f, 0.f, 0.f};
    #pragma unroll
    for (int a = 0; a < 2; ++a)
        #pragma unroll
        for (int b = 0; b < 8; ++b) { accN[a][b] = zero; accC[a][b] = zero; }

    const int arow0 = (w * 32 + ln) * MIS;
    const int arow1 = (w * 32 + 16 + ln) * MIS;
    const int koff  = quad * 8;

    #pragma unroll
    for (int pass = 0; pass < 4; ++pass) {
        const int mat = pass >> 1, half = pass & 1;   // mat 0=node,1=coord
        const unsigned short* wsrc = ws + mat * 20480 + half * 64 * 160;
        __syncthreads();   // previous pass's reads done before overwriting wbuf
        #pragma unroll
        for (int c = 0; c < 5; ++c) {
            int idx = c * 256 + tid;                  // 1280 = 64 rows * 20 chunks
            int row = idx / 20, col8 = idx % 20;
            *(uint4*)&wbuf[row * MIS + col8 * 8] =
                *(const uint4*)(wsrc + row * 160 + col8 * 8);
        }
        __syncthreads();
        #pragma unroll
        for (int kc = 0; kc < 5; ++kc) {
            short8 a0 = *(const short8*)&mi[arow0 + kc * 32 + koff];
            short8 a1 = *(const short8*)&mi[arow1 + kc * 32 + koff];
            #pragma unroll
            for (int nt = 0; nt < 4; ++nt) {
                short8 b = *(const short8*)&wbuf[(nt * 16 + ln) * MIS + kc * 32 + koff];
                const int nn = half * 4 + nt;
                if (mat == 0) {
                    accN[0][nn] = __builtin_amdgcn_mfma_f32_16x16x32_bf16(a0, b, accN[0][nn], 0, 0, 0);
                    accN[1][nn] = __builtin_amdgcn_mfma_f32_16x16x32_bf16(a1, b, accN[1][nn], 0, 0, 0);
                } else {
                    accC[0][nn] = __builtin_amdgcn_mfma_f32_16x16x32_bf16(a0, b, accC[0][nn], 0, 0, 0);
                    accC[1][nn] = __builtin_amdgcn_mfma_f32_16x16x32_bf16(a1, b, accC[1][nn], 0, 0, 0);
                }
            }
        }
    }

    // ---- hidden = silu(accN + b1) -> bf16, overwrite m_input tile ----
    __syncthreads();   // all GEMM1 reads of mi complete
    #pragma unroll
    for (int mt = 0; mt < 2; ++mt) {
        const int rowb = (w * 32 + mt * 16 + quad * 4) * MIS;
        #pragma unroll
        for (int nt = 0; nt < 8; ++nt) {
            int col = nt * 16 + ln;
            float b1v = node_b1[col];
            #pragma unroll
            for (int r = 0; r < 4; ++r)
                mi[rowb + r * MIS + col] = f2bf(silu_f(accN[mt][nt][r] + b1v));
        }
    }
    __syncthreads();

    // ---- GEMM2-node: [128,128] @ [128,64] ----
    f32x4 acc2[2][4];
    #pragma unroll
    for (int a = 0; a < 2; ++a)
        #pragma unroll
        for (int b = 0; b < 4; ++b) acc2[a][b] = zero;
    const unsigned short* nw2T = ws + 40960;
    #pragma unroll
    for (int kc = 0; kc < 4; ++kc) {
        short8 a0 = *(const short8*)&mi[arow0 + kc * 32 + koff];
        short8 a1 = *(const short8*)&mi[arow1 + kc * 32 + koff];
        #pragma unroll
        for (int nt = 0; nt < 4; ++nt) {
            short8 b = *(const short8*)(nw2T + (nt * 16 + ln) * 128 + kc * 32 + koff);
            acc2[0][nt] = __builtin_amdgcn_mfma_f32_16x16x32_bf16(a0, b, acc2[0][nt], 0, 0, 0);
            acc2[1][nt] = __builtin_amdgcn_mfma_f32_16x16x32_bf16(a1, b, acc2[1][nt], 0, 0, 0);
        }
    }
    // ---- node scatter: out_h[dst] += m + b2 ----
    #pragma unroll
    for (int mt = 0; mt < 2; ++mt) {
        #pragma unroll
        for (int r = 0; r < 4; ++r) {
            int lrow = w * 32 + mt * 16 + quad * 4 + r;
            int dn = eidx[NE + e0 + lrow];
            float* outrow = out_h + (size_t)dn * 64;
            #pragma unroll
            for (int nt = 0; nt < 4; ++nt) {
                int col = nt * 16 + ln;
                atomicAdd(outrow + col, acc2[mt][nt][r] + node_b2[col]);
            }
        }
    }

    // ---- coord path: cw[e] = silu(accC + b1c) . w2c ----
    float cw[2][4];
    #pragma unroll
    for (int mt = 0; mt < 2; ++mt)
        #pragma unroll
        for (int r = 0; r < 4; ++r) cw[mt][r] = 0.f;
    #pragma unroll
    for (int nt = 0; nt < 8; ++nt) {
        int col = nt * 16 + ln;
        float b1v = coord_b1[col];
        float w2v = coord_w2[col];
        #pragma unroll
        for (int mt = 0; mt < 2; ++mt)
            #pragma unroll
            for (int r = 0; r < 4; ++r)
                cw[mt][r] += silu_f(accC[mt][nt][r] + b1v) * w2v;
    }
    #pragma unroll
    for (int off = 1; off < 16; off <<= 1) {
        #pragma unroll
        for (int mt = 0; mt < 2; ++mt)
            #pragma unroll
            for (int r = 0; r < 4; ++r)
                cw[mt][r] += __shfl_xor(cw[mt][r], off, 64);
    }
    // lanes ln<8 per quad each handle one (mt,r) edge
    if (ln < 8) {
        const int smt = ln >> 2, sr = ln & 3;
        float cwsel = 0.f;
        #pragma unroll
        for (int mt = 0; mt < 2; ++mt)
            #pragma unroll
            for (int r = 0; r < 4; ++r)
                cwsel = (mt == smt && r == sr) ? cw[mt][r] : cwsel;
        int lrow = w * 32 + smt * 16 + quad * 4 + sr;
        int s = eidx[e0 + lrow], dn = eidx[NE + e0 + lrow];
        float dx = x[s * 3]     - x[dn * 3];
        float dy = x[s * 3 + 1] - x[dn * 3 + 1];
        float dz = x[s * 3 + 2] - x[dn * 3 + 2];
        float len = fmaxf(sqrtf(dx * dx + dy * dy + dz * dz), 1e-8f);
        float k = cwsel / len;
        atomicAdd(out_x + dn * 3,     k * dx);
        atomicAdd(out_x + dn * 3 + 1, k * dy);
        atomicAdd(out_x + dn * 3 + 2, k * dz);
    }
}

extern "C" void kernel_launch(void* const* d_in, const int* in_sizes, int n_in,
                              void* d_out, int out_size, void* d_ws, size_t ws_size,
                              hipStream_t stream) {
    const float* h    = (const float*)d_in[0];
    const float* x    = (const float*)d_in[1];
    const int*   eidx = (const int*)d_in[2];
    const float* edist= (const float*)d_in[3];
    const float* nw1  = (const float*)d_in[4];
    const float* nb1  = (const float*)d_in[5];
    const float* nw2  = (const float*)d_in[6];
    const float* nb2  = (const float*)d_in[7];
    const float* cw1  = (const float*)d_in[8];
    const float* cb1  = (const float*)d_in[9];
    const float* cw2  = (const float*)d_in[10];
    const float* ew1  = (const float*)d_in[11];
    const float* eb1  = (const float*)d_in[12];
    const float* ew2  = (const float*)d_in[13];
    const float* eb2  = (const float*)d_in[14];
    float* out = (float*)d_out;
    unsigned short* ws = (unsigned short*)d_ws;

    prep_kernel<<<192, 256, 0, stream>>>(nw1, cw1, nw2, ws);
    init_out<<<3272, 256, 0, stream>>>((const float4*)h, (const float4*)x, (float4*)out);
    egnn_edge_kernel<<<NE / BE, 256, 0, stream>>>(h, x, eidx, edist,
                                                  nb1, nb2, cb1, cw2,
                                                  ew1, eb1, ew2, eb2,
                                                  ws, out, out + 3200000);
}